// Round 4
// baseline (106.828 us; speedup 1.0000x reference)
//
#include <hip/hip_runtime.h>
#include <hip/hip_bf16.h>

typedef __attribute__((ext_vector_type(8))) int i32x8;
typedef __attribute__((ext_vector_type(4))) int i32x4;
typedef __attribute__((ext_vector_type(4))) float f32x4;

#define NB 4096
#define ND 512
#define MARGIN_F 0.2f
#define UNIT_SCALE 0x7F7F7F7F   // e8m0 1.0 in every byte -> opsel-insensitive

// order-preserving float -> uint encoding for atomicMax.
// enc(f) == 0 is impossible for finite f, so rowmax[a] == 0  <=>
// no wave ever found a different-label column in row a (has_neg == false).
__device__ __forceinline__ unsigned int enc_f32(float f) {
    unsigned int b = __float_as_uint(f);
    return (b & 0x80000000u) ? ~b : (b | 0x80000000u);
}

__device__ __forceinline__ float dec_f32(unsigned int e) {
    unsigned int b = (e & 0x80000000u) ? (e & 0x7fffffffu) : ~e;
    return __uint_as_float(b);
}

__device__ __forceinline__ void gld_lds16(const void* g, void* l) {
    __builtin_amdgcn_global_load_lds((__attribute__((address_space(1))) void*)g,
                                     (__attribute__((address_space(3))) void*)l,
                                     16, 0, 0);
}

// ---------------------------------------------------------------------------
// Prep: fp32 -> fp8 e4m3 (OCP, HW cvt), fragment-swizzled for 16x16x128 MFMA.
// Subtile = 16 rows x 128 k (2048 B). si = (row/16)*4 + (k/128).
// Lane L = (row%16) | (((k%128)/32)<<4) holds k-bytes j=k%32, split in two
// 1024 B planes (j<16 -> plane0 at lane*16+j; j>=16 -> plane1).
// Each thread produces one 16 B plane-line from 16 consecutive k (64 B read).
// Blocks [0,16) also zero the 4096-entry rowmax array.
// ---------------------------------------------------------------------------
__global__ __launch_bounds__(256) void k_prep(const float* __restrict__ zs,
                                              const float* __restrict__ zi,
                                              unsigned char* __restrict__ outb,
                                              unsigned int* __restrict__ rowmax) {
    const int bid = blockIdx.x;
    if (bid < 16) rowmax[bid * 256 + threadIdx.x] = 0u;

    int gid = bid * 256 + threadIdx.x;   // [0, 262144) chunks of 16 B
    int mat = gid >> 17;                 // 0 = zs, 1 = zi (2 MB each)
    int c   = gid & 0x1FFFF;
    int si  = c >> 7;                    // subtile (2048 B = 128 chunks)
    int w   = c & 127;
    int plane = w >> 6, lane = w & 63;
    int row = ((si >> 2) << 4) | (lane & 15);
    int kb  = ((si & 3) << 7) | (((lane >> 4) & 3) << 5) | (plane << 4);
    const float* src = (mat ? zi : zs) + (size_t)row * ND + kb;

    int4 o;
    int* op = (int*)&o;
#pragma unroll
    for (int q = 0; q < 4; ++q) {
        float4 f = ((const float4*)src)[q];
        int r = 0;
        r = __builtin_amdgcn_cvt_pk_fp8_f32(f.x, f.y, r, false);  // bytes 0-1
        r = __builtin_amdgcn_cvt_pk_fp8_f32(f.z, f.w, r, true);   // bytes 2-3
        op[q] = r;
    }
    *(int4*)(outb + ((size_t)mat << 21) + ((size_t)c << 4)) = o;
}

// ---------------------------------------------------------------------------
// 128x128 tile GEMM (S = Zs . Zi^T), fp8 e4m3 via mfma_scale 16x16x128 with
// unit scales (2x bf16 rate, no block-scale layout hazard). BK=128, 4 K-steps,
// 4 waves, wave tile 64x64 as 4x4 subtiles. Epilogue: per-row different-label
// max -> atomicMax (C/D layout is shape-determined: col=lane&15, row=quad*4+r).
// Diagonal blocks also extract p_diag[a] = 1 - S[a][a].
// ---------------------------------------------------------------------------
__global__ __launch_bounds__(256) void k_gemm_rowmax(const unsigned char* __restrict__ zsb,
                                                     const unsigned char* __restrict__ zib,
                                                     const int* __restrict__ labels,
                                                     unsigned int* __restrict__ rowmax,
                                                     float* __restrict__ p_diag) {
    __shared__ __align__(16) unsigned char sA[16384];   // 8 subtiles x 2 KB
    __shared__ __align__(16) unsigned char sB[16384];
    __shared__ int labA[128];
    __shared__ int labB[128];

    const int tid = threadIdx.x;
    const int bx = blockIdx.x, by = blockIdx.y;

    if (tid < 128) labA[tid] = labels[by * 128 + tid];
    else           labB[tid - 128] = labels[bx * 128 + (tid - 128)];

    const char* gA = (const char*)zsb;
    const char* gB = (const char*)zib;
    const int rb0 = tid >> 7;              // 0/1
    const int rem = (tid & 127) << 4;      // [0,2048) within subtile, 1:1 copy
    size_t aStat[4], bStat[4];
#pragma unroll
    for (int rd = 0; rd < 4; ++rd) {
        int rb = rd * 2 + rb0;             // local row-block 0..7
        aStat[rd] = ((size_t)(by * 8 + rb) << 13) + rem;   // row-block = 8192 B
        bStat[rd] = ((size_t)(bx * 8 + rb) << 13) + rem;
    }

    const int w = tid >> 6, lane = tid & 63;
    const int w_m = w >> 1, w_n = w & 1;
    const int fragOff = lane << 4;

    f32x4 acc[4][4];
#pragma unroll
    for (int i = 0; i < 4; ++i)
#pragma unroll
        for (int j = 0; j < 4; ++j)
            acc[i][j] = (f32x4){0.f, 0.f, 0.f, 0.f};

    for (int ks = 0; ks < 4; ++ks) {
        __syncthreads();
#pragma unroll
        for (int rd = 0; rd < 4; ++rd) {
            gld_lds16(gA + aStat[rd] + (size_t)ks * 2048, sA + rd * 4096 + (tid << 4));
            gld_lds16(gB + bStat[rd] + (size_t)ks * 2048, sB + rd * 4096 + (tid << 4));
        }
        __syncthreads();

        i32x8 af[4], bfr[4];
#pragma unroll
        for (int ms = 0; ms < 4; ++ms) {
            const unsigned char* base = sA + ((w_m * 4 + ms) << 11) + fragOff;
            i32x4 lo = *(const i32x4*)base;
            i32x4 hi = *(const i32x4*)(base + 1024);
            af[ms] = (i32x8){lo.x, lo.y, lo.z, lo.w, hi.x, hi.y, hi.z, hi.w};
        }
#pragma unroll
        for (int ns = 0; ns < 4; ++ns) {
            const unsigned char* base = sB + ((w_n * 4 + ns) << 11) + fragOff;
            i32x4 lo = *(const i32x4*)base;
            i32x4 hi = *(const i32x4*)(base + 1024);
            bfr[ns] = (i32x8){lo.x, lo.y, lo.z, lo.w, hi.x, hi.y, hi.z, hi.w};
        }
#pragma unroll
        for (int ms = 0; ms < 4; ++ms)
#pragma unroll
            for (int ns = 0; ns < 4; ++ns)
                acc[ms][ns] = __builtin_amdgcn_mfma_scale_f32_16x16x128_f8f6f4(
                    af[ms], bfr[ns], acc[ms][ns],
                    0, 0,                      // cbsz=fp8(e4m3), blgp=fp8(e4m3)
                    0, UNIT_SCALE,             // opsel_a, scale_a = 1.0
                    0, UNIT_SCALE);            // opsel_b, scale_b = 1.0
    }

    // epilogue: C/D layout col = lane&15, row = (lane>>4)*4 + reg
    const int quad = lane >> 4;
    const int lcol = lane & 15;

    int lb[4];
#pragma unroll
    for (int ns = 0; ns < 4; ++ns)
        lb[ns] = labB[w_n * 64 + ns * 16 + lcol];

#pragma unroll
    for (int ms = 0; ms < 4; ++ms) {
        int la[4];
#pragma unroll
        for (int r = 0; r < 4; ++r)
            la[r] = labA[w_m * 64 + ms * 16 + quad * 4 + r];
        float mx[4] = {-3.0e38f, -3.0e38f, -3.0e38f, -3.0e38f};
#pragma unroll
        for (int ns = 0; ns < 4; ++ns) {
#pragma unroll
            for (int r = 0; r < 4; ++r) {
                float v = acc[ms][ns][r];
                if (la[r] != lb[ns] && v > mx[r]) mx[r] = v;
            }
        }
#pragma unroll
        for (int r = 0; r < 4; ++r) {
            float m = mx[r];
            m = fmaxf(m, __shfl_xor(m, 1));
            m = fmaxf(m, __shfl_xor(m, 2));
            m = fmaxf(m, __shfl_xor(m, 4));
            m = fmaxf(m, __shfl_xor(m, 8));
            // skip if this wave's 16-col slice had no different-label column
            if (lcol == 0 && m > -2.9e38f) {
                int rowg = by * 128 + w_m * 64 + ms * 16 + quad * 4 + r;
                atomicMax(&rowmax[rowg], enc_f32(m));
            }
        }
    }

    // diagonal blocks: extract p[a] = 1 - S[a][a].
    if (bx == by && w_m == w_n) {
        int r = lcol - quad * 4;
        if (r >= 0 && r < 4) {
#pragma unroll
            for (int ms = 0; ms < 4; ++ms) {
                int rowg = by * 128 + w_m * 64 + ms * 16 + lcol;
                p_diag[rowg] = 1.0f - acc[ms][ms][r];
            }
        }
    }
}

// ---------------------------------------------------------------------------
// Finalize: has_neg = (rowmax != 0); n = 1 - dec(rowmax);
// per = relu(p - n + margin); masked mean -> out[0]
// ---------------------------------------------------------------------------
__global__ __launch_bounds__(1024) void k_finalize(const unsigned int* __restrict__ rowmax,
                                                   const float* __restrict__ p_diag,
                                                   float* __restrict__ out) {
    int tid = threadIdx.x;
    float sum = 0.0f;
    int cnt = 0;
#pragma unroll
    for (int it = 0; it < 4; ++it) {
        int a = tid + it * 1024;
        unsigned int e = rowmax[a];
        if (e != 0u) {
            float n = 1.0f - dec_f32(e);
            float per = p_diag[a] - n + MARGIN_F;
            if (per > 0.0f) sum += per;
            cnt++;
        }
    }
#pragma unroll
    for (int off = 32; off > 0; off >>= 1) {
        sum += __shfl_xor(sum, off);
        cnt += __shfl_xor(cnt, off);
    }
    __shared__ float sSum[16];
    __shared__ int sCnt[16];
    int w = tid >> 6, lane = tid & 63;
    if (lane == 0) { sSum[w] = sum; sCnt[w] = cnt; }
    __syncthreads();
    if (tid == 0) {
        float ts = 0.0f;
        int tc = 0;
#pragma unroll
        for (int i = 0; i < 16; ++i) { ts += sSum[i]; tc += sCnt[i]; }
        out[0] = (tc > 0) ? ts / (float)tc : 0.0f;
    }
}

extern "C" void kernel_launch(void* const* d_in, const int* in_sizes, int n_in,
                              void* d_out, int out_size, void* d_ws, size_t ws_size,
                              hipStream_t stream) {
    (void)in_sizes; (void)n_in; (void)out_size; (void)ws_size;
    const float* zs = (const float*)d_in[0];
    const float* zi = (const float*)d_in[1];
    const int* labels = (const int*)d_in[2];
    float* out = (float*)d_out;

    char* ws = (char*)d_ws;
    unsigned char* zb = (unsigned char*)ws;                         // 4 MB (zs then zi, fp8 swizzled)
    unsigned int* rowmax = (unsigned int*)(ws + (4u << 20));        // 16 KB
    float* p_diag = (float*)(ws + (4u << 20) + 16384);              // 16 KB

    k_prep<<<1024, 256, 0, stream>>>(zs, zi, zb, rowmax);
    dim3 g(32, 32);
    k_gemm_rowmax<<<g, 256, 0, stream>>>(zb, zb + (2u << 20), labels, rowmax, p_diag);
    k_finalize<<<1, 1024, 0, stream>>>(rowmax, p_diag, out);
}